// Round 1
// baseline (238.884 us; speedup 1.0000x reference)
//
#include <hip/hip_runtime.h>

#define NUM_LAYERS 24
#define LN_EPS 1e-5f
#define N_ROWS (256 * 8192)

// One thread = one row. Weights are wave-uniform -> compiler should emit
// s_load into SGPRs; each inner FMA is v_fmac_f32 vdst, sgpr, vgpr.
// h1[64] lives in VGPRs (fully unrolled indexing).
__global__ __launch_bounds__(256, 4) void router_kernel(
    const float* __restrict__ x,
    const float* __restrict__ ln_w,
    const float* __restrict__ ln_b,
    const float* __restrict__ W1,
    const float* __restrict__ b1,
    const float* __restrict__ W2,
    const float* __restrict__ b2,
    const float* __restrict__ W3,
    const float* __restrict__ b3,
    float* __restrict__ out)
{
    __shared__ float s_lnw[NUM_LAYERS * 4];
    __shared__ float s_lnb[NUM_LAYERS * 4];

    const int t = threadIdx.x;
    if (t < NUM_LAYERS * 4) {
        s_lnw[t] = ln_w[t];
        s_lnb[t] = ln_b[t];
    }
    __syncthreads();

    const int row = blockIdx.x * 256 + t;
    if (row >= N_ROWS) return;

    const float* xp = x + (size_t)row * 5;
    const float f0 = xp[0];
    const float f1 = xp[1];
    const float f2 = xp[2];
    const float f3 = xp[3];
    const float lp = xp[4];

    // layer id: trunc toward zero matches .astype(int32) for lp in [0,1)
    int lid = (int)(lp * (float)NUM_LAYERS);
    lid = lid < 0 ? 0 : (lid > NUM_LAYERS - 1 ? NUM_LAYERS - 1 : lid);

    // LayerNorm over the 4 features
    const float m = (f0 + f1 + f2 + f3) * 0.25f;
    const float d0 = f0 - m, d1 = f1 - m, d2 = f2 - m, d3 = f3 - m;
    const float var = (d0 * d0 + d1 * d1 + d2 * d2 + d3 * d3) * 0.25f;
    const float r = rsqrtf(var + LN_EPS);

    const float4 g  = *(const float4*)(&s_lnw[lid * 4]);
    const float4 bb = *(const float4*)(&s_lnb[lid * 4]);

    const float xn0 = d0 * r * g.x + bb.x;
    const float xn1 = d1 * r * g.y + bb.y;
    const float xn2 = d2 * r * g.z + bb.z;
    const float xn3 = d3 * r * g.w + bb.w;
    const float xn4 = lp;

    // Layer 1: 5 -> 64, relu
    float h1[64];
#pragma unroll
    for (int j = 0; j < 64; ++j) {
        float acc = b1[j];
        acc = fmaf(xn0, W1[j * 5 + 0], acc);
        acc = fmaf(xn1, W1[j * 5 + 1], acc);
        acc = fmaf(xn2, W1[j * 5 + 2], acc);
        acc = fmaf(xn3, W1[j * 5 + 3], acc);
        acc = fmaf(xn4, W1[j * 5 + 4], acc);
        h1[j] = fmaxf(acc, 0.0f);
    }

    // Layer 2: 64 -> 32, relu
    float h2[32];
#pragma unroll
    for (int j = 0; j < 32; ++j) {
        float acc = b2[j];
#pragma unroll
        for (int k = 0; k < 64; ++k) {
            acc = fmaf(h1[k], W2[j * 64 + k], acc);
        }
        h2[j] = fmaxf(acc, 0.0f);
    }

    // Layer 3: 32 -> 1
    float sc = b3[0];
#pragma unroll
    for (int k = 0; k < 32; ++k) {
        sc = fmaf(h2[k], W3[k], sc);
    }

    out[row] = sc;
}

extern "C" void kernel_launch(void* const* d_in, const int* in_sizes, int n_in,
                              void* d_out, int out_size, void* d_ws, size_t ws_size,
                              hipStream_t stream) {
    const float* x    = (const float*)d_in[0];
    const float* ln_w = (const float*)d_in[1];
    const float* ln_b = (const float*)d_in[2];
    const float* W1   = (const float*)d_in[3];
    const float* b1   = (const float*)d_in[4];
    const float* W2   = (const float*)d_in[5];
    const float* b2   = (const float*)d_in[6];
    const float* W3   = (const float*)d_in[7];
    const float* b3   = (const float*)d_in[8];
    float* out = (float*)d_out;

    const int blocks = (N_ROWS + 255) / 256;  // 8192
    router_kernel<<<blocks, 256, 0, stream>>>(x, ln_w, ln_b, W1, b1, W2, b2,
                                              W3, b3, out);
}

// Round 2
// 134.554 us; speedup vs baseline: 1.7754x; 1.7754x over previous
//
#include <hip/hip_runtime.h>
#include <hip/hip_bf16.h>
#include <stdint.h>

#define NUM_LAYERS 24
#define LN_EPS 1e-5f
#define N_ROWS (256 * 8192)
#define ROWS_PER_ITER 32
#define NUM_ITERS (N_ROWS / ROWS_PER_ITER)   // 65536
#define NUM_BLOCKS 2048                       // 8192 waves -> 8 iters/wave

typedef __attribute__((ext_vector_type(8)))  short bf16x8;   // 8 bf16 = 4 VGPRs
typedef __attribute__((ext_vector_type(16))) float f32x16;   // 32x32 MFMA acc

// pack two f32 -> one dword of 2 bf16 (lo = first arg), RNE
__device__ __forceinline__ uint32_t pk_bf16(float lo, float hi) {
    __hip_bfloat162 h2 = __float22bfloat162_rn(float2{lo, hi});
    uint32_t u;
    __builtin_memcpy(&u, &h2, 4);
    return u;
}

union FragU { bf16x8 f; uint32_t u[4]; };

__device__ __forceinline__ bf16x8 make_frag(uint32_t d0, uint32_t d1,
                                            uint32_t d2, uint32_t d3) {
    FragU fu;
    fu.u[0] = d0; fu.u[1] = d1; fu.u[2] = d2; fu.u[3] = d3;
    return fu.f;
}

// canonical hidden index k placed at layer1-output row-position p (sigma).
// Derivation: C1 (32x32 C-layout) reg r, lane-half h, m-tile mt holds
// position p = 32*mt + (r&3) + 8*(r>>2) + 4*h. We need that position to
// carry canonical k = 16*(2*mt + (r>>3)) + 8*h + (r&7) so that layer2
// A-fragment slot (kt = 2*mt + (r>>3), j = r&7) is correct for BOTH halves.
__device__ __forceinline__ int sigma_k(int p) {
    int hh = (p >> 2) & 1;
    int base = (p & 31) - 4 * hh;            // in {0-3,8-11,16-19,24-27}
    int r = (base & 3) + 4 * (base >> 3);    // in [0,16)
    return 32 * (p >> 5) + 16 * (r >> 3) + 8 * hh + (r & 7);
}

__global__ __launch_bounds__(256, 4) void router_mfma(
    const float* __restrict__ x,
    const float* __restrict__ ln_w,
    const float* __restrict__ ln_b,
    const float* __restrict__ W1,
    const float* __restrict__ b1,
    const float* __restrict__ W2,
    const float* __restrict__ b2,
    const float* __restrict__ W3,
    const float* __restrict__ b3,
    float* __restrict__ out)
{
    // ln_w/ln_b interleaved per lid: [g0..g3, b0..b3] (32B per lid)
    __shared__ float s_ln[NUM_LAYERS * 8];
    const int t = threadIdx.x;
    if (t < NUM_LAYERS * 4) {
        int lid = t >> 2, c = t & 3;
        s_ln[lid * 8 + c]     = ln_w[t];
        s_ln[lid * 8 + 4 + c] = ln_b[t];
    }
    __syncthreads();

    const int lane = t & 63;
    const int wid  = t >> 6;
    const int n32  = lane & 31;   // data-row within tile / weight output unit
    const int h    = lane >> 5;   // lane half

    // ---------- preload weight fragments (once per thread) ----------
    // Layer1 A-frags (2 m-tiles of hidden positions). A[p][q], q in [0,16):
    // q<5 = W1[k][q], q==5 = b1[k] (bias folded via B1[5][n]=1), rest 0.
    // Lane holds m = lane&31 (p = 32*mt + m), q = 8*h + j -> h==1 lanes all 0.
    bf16x8 a1f[2];
#pragma unroll
    for (int mt = 0; mt < 2; ++mt) {
        int p = mt * 32 + n32;
        int k = sigma_k(p);
        float w0 = W1[k * 5 + 0], w1 = W1[k * 5 + 1], w2 = W1[k * 5 + 2];
        float w3 = W1[k * 5 + 3], w4 = W1[k * 5 + 4];
        float bc = b1[k];
        uint32_t d0 = pk_bf16(w0, w1);
        uint32_t d1 = pk_bf16(w2, w3);
        uint32_t d2 = pk_bf16(w4, bc);
        if (h) { d0 = 0; d1 = 0; d2 = 0; }
        a1f[mt] = make_frag(d0, d1, d2, 0);
    }

    // Layer2 B-frags (4 k-tiles). B[k][n] = W2[n][k]; lane holds n = lane&31,
    // k = 16*kt + 8*h + j -> 8 consecutive floats of W2 row n (32B aligned).
    bf16x8 b2f[4];
#pragma unroll
    for (int kt = 0; kt < 4; ++kt) {
        const float* wp = W2 + n32 * 64 + kt * 16 + h * 8;
        const float4 lo = *(const float4*)(wp);
        const float4 hi = *(const float4*)(wp + 4);
        b2f[kt] = make_frag(pk_bf16(lo.x, lo.y), pk_bf16(lo.z, lo.w),
                            pk_bf16(hi.x, hi.y), pk_bf16(hi.z, hi.w));
    }

    const float b2v = b2[n32];
    const float w3v = W3[n32];
    const float b3v = b3[0];

    const int total_waves = NUM_BLOCKS * 4;
    const int w = blockIdx.x * 4 + wid;

    for (int it = w; it < NUM_ITERS; it += total_waves) {
        const int rowBase = it * ROWS_PER_ITER;

        // ---- per-lane LayerNorm (both halves redundantly compute row n32) ----
        const float* xp = x + (size_t)(rowBase + n32) * 5;
        const float f0 = xp[0], f1 = xp[1], f2 = xp[2], f3 = xp[3], lp = xp[4];

        int lid = (int)(lp * (float)NUM_LAYERS);
        lid = lid < 0 ? 0 : (lid > NUM_LAYERS - 1 ? NUM_LAYERS - 1 : lid);

        const float m  = (f0 + f1 + f2 + f3) * 0.25f;
        const float d0 = f0 - m, d1 = f1 - m, d2 = f2 - m, d3 = f3 - m;
        const float var = (d0 * d0 + d1 * d1 + d2 * d2 + d3 * d3) * 0.25f;
        const float r   = rsqrtf(var + LN_EPS);

        const float4 g  = *(const float4*)(s_ln + lid * 8);
        const float4 bb = *(const float4*)(s_ln + lid * 8 + 4);

        const float xn0 = fmaf(d0 * r, g.x, bb.x);
        const float xn1 = fmaf(d1 * r, g.y, bb.y);
        const float xn2 = fmaf(d2 * r, g.z, bb.z);
        const float xn3 = fmaf(d3 * r, g.w, bb.w);

        // ---- B1 fragment: xn^T, column of 1.0 at q=5 for the b1 fold ----
        uint32_t e0 = pk_bf16(xn0, xn1);
        uint32_t e1 = pk_bf16(xn2, xn3);
        uint32_t e2 = pk_bf16(lp, 1.0f);
        if (h) { e0 = 0; e1 = 0; e2 = 0; }
        const bf16x8 b1f = make_frag(e0, e1, e2, 0);

        // ---- layer 1: h1^T = A1 . xn^T  (2 MFMAs) ----
        f32x16 z;
#pragma unroll
        for (int i = 0; i < 16; ++i) z[i] = 0.0f;
        f32x16 c1a = __builtin_amdgcn_mfma_f32_32x32x16_bf16(a1f[0], b1f, z, 0, 0, 0);
        f32x16 c1b = __builtin_amdgcn_mfma_f32_32x32x16_bf16(a1f[1], b1f, z, 0, 0, 0);

        // ---- relu + repack C1 regs directly into layer2 A-frags ----
        // A2[kt] dword d = pk( relu(C1[kt>>1][8*(kt&1)+2d]), relu(...+2d+1) )
        bf16x8 a2f[4];
#pragma unroll
        for (int kt = 0; kt < 4; ++kt) {
            const f32x16& c1 = (kt < 2) ? c1a : c1b;
            const int roff = 8 * (kt & 1);
            uint32_t dw[4];
#pragma unroll
            for (int d = 0; d < 4; ++d) {
                float va = fmaxf(c1[roff + 2 * d], 0.0f);
                float vb = fmaxf(c1[roff + 2 * d + 1], 0.0f);
                dw[d] = pk_bf16(va, vb);
            }
            a2f[kt] = make_frag(dw[0], dw[1], dw[2], dw[3]);
        }

        // ---- layer 2: C2 = h1 . W2^T + b2  (4 MFMAs, b2 in acc init) ----
        f32x16 c2;
#pragma unroll
        for (int i = 0; i < 16; ++i) c2[i] = b2v;
#pragma unroll
        for (int kt = 0; kt < 4; ++kt)
            c2 = __builtin_amdgcn_mfma_f32_32x32x16_bf16(a2f[kt], b2f[kt], c2, 0, 0, 0);

        // ---- layer 3: score[row] = b3 + sum_n W3[n]*relu(C2[row][n]) ----
        // C2: lane holds out-unit n = lane&31, rows (reg&3)+8*(reg>>2)+4*h.
        // Pairwise row-merge shuffle tree: xor16 partial, select rows, xor8..1.
        float vc[8];
#pragma unroll
        for (int p = 0; p < 8; ++p) {
            float va = fmaxf(c2[2 * p], 0.0f) * w3v;
            float vb = fmaxf(c2[2 * p + 1], 0.0f) * w3v;
            va += __shfl_xor(va, 16, 64);
            vb += __shfl_xor(vb, 16, 64);
            float vm = (lane & 16) ? vb : va;
            vm += __shfl_xor(vm, 8, 64);
            vm += __shfl_xor(vm, 4, 64);
            vm += __shfl_xor(vm, 2, 64);
            vm += __shfl_xor(vm, 1, 64);
            vc[p] = vm;
        }
        // row of vc[p] on this lane: base(2p) + ((lane>>4)&1) + 4*h
        const int pid = lane & 15;
        if (pid < 8) {
            float v = vc[0];
#pragma unroll
            for (int p = 1; p < 8; ++p) v = (pid == p) ? vc[p] : v;
            const int base2 = ((2 * pid) & 3) + 8 * (pid >> 1);
            const int dr = base2 + ((lane >> 4) & 1) + 4 * h;
            out[rowBase + dr] = v + b3v;
        }
    }
}

extern "C" void kernel_launch(void* const* d_in, const int* in_sizes, int n_in,
                              void* d_out, int out_size, void* d_ws, size_t ws_size,
                              hipStream_t stream) {
    const float* x    = (const float*)d_in[0];
    const float* ln_w = (const float*)d_in[1];
    const float* ln_b = (const float*)d_in[2];
    const float* W1   = (const float*)d_in[3];
    const float* b1   = (const float*)d_in[4];
    const float* W2   = (const float*)d_in[5];
    const float* b2   = (const float*)d_in[6];
    const float* W3   = (const float*)d_in[7];
    const float* b3   = (const float*)d_in[8];
    float* out = (float*)d_out;

    router_mfma<<<NUM_BLOCKS, 256, 0, stream>>>(x, ln_w, ln_b, W1, b1, W2, b2,
                                                W3, b3, out);
}

// Round 3
// 122.565 us; speedup vs baseline: 1.9490x; 1.0978x over previous
//
#include <hip/hip_runtime.h>
#include <hip/hip_bf16.h>
#include <stdint.h>

#define NUM_LAYERS 24
#define LN_EPS 1e-5f
#define N_ROWS (256 * 8192)
#define ROWS_PER_ITER 32
#define NUM_ITERS (N_ROWS / ROWS_PER_ITER)   // 65536
#define NUM_BLOCKS 2048                       // 8192 waves -> 8 iters/wave

typedef __attribute__((ext_vector_type(8)))  short bf16x8;   // 8 bf16 = 4 VGPRs
typedef __attribute__((ext_vector_type(16))) float f32x16;   // 32x32 MFMA acc

// pack two f32 -> one dword of 2 bf16 (lo = first arg), RNE
__device__ __forceinline__ uint32_t pk_bf16(float lo, float hi) {
    __hip_bfloat162 h2 = __float22bfloat162_rn(float2{lo, hi});
    uint32_t u;
    __builtin_memcpy(&u, &h2, 4);
    return u;
}

union FragU { bf16x8 f; uint32_t u[4]; };

__device__ __forceinline__ bf16x8 make_frag(uint32_t d0, uint32_t d1,
                                            uint32_t d2, uint32_t d3) {
    FragU fu;
    fu.u[0] = d0; fu.u[1] = d1; fu.u[2] = d2; fu.u[3] = d3;
    return fu.f;
}

// canonical hidden index k placed at layer1-output row-position p (sigma).
// C1 (32x32 C-layout) reg r, lane-half hh, m-tile mt holds position
// p = 32*mt + (r&3) + 8*(r>>2) + 4*hh. We need that position to carry
// canonical k = 16*(2*mt + (r>>3)) + 8*hh + (r&7) so that the layer2
// h1-fragment slot (kt = 2*mt + (r>>3), j = r&7) is correct for BOTH halves.
__device__ __forceinline__ int sigma_k(int p) {
    int hh = (p >> 2) & 1;
    int base = (p & 31) - 4 * hh;            // in {0-3,8-11,16-19,24-27}
    int r = (base & 3) + 4 * (base >> 3);    // in [0,16)
    return 32 * (p >> 5) + 16 * (r >> 3) + 8 * hh + (r & 7);
}

__global__ __launch_bounds__(256, 4) void router_mfma(
    const float* __restrict__ x,
    const float* __restrict__ ln_w,
    const float* __restrict__ ln_b,
    const float* __restrict__ W1,
    const float* __restrict__ b1,
    const float* __restrict__ W2,
    const float* __restrict__ b2,
    const float* __restrict__ W3,
    const float* __restrict__ b3,
    float* __restrict__ out)
{
    // ln_w/ln_b interleaved per lid: [g0..g3, b0..b3] (32B per lid)
    __shared__ float s_ln[NUM_LAYERS * 8];
    const int t = threadIdx.x;
    if (t < NUM_LAYERS * 4) {
        int lid = t >> 2, c = t & 3;
        s_ln[lid * 8 + c]     = ln_w[t];
        s_ln[lid * 8 + 4 + c] = ln_b[t];
    }
    __syncthreads();

    const int lane = t & 63;
    const int wid  = t >> 6;
    const int n32  = lane & 31;   // data-row within tile / weight output unit
    const int h    = lane >> 5;   // lane half

    // ---------- preload weight fragments (once per thread) ----------
    // Layer1 A-frags (2 m-tiles of hidden positions). A[p][q], q in [0,16):
    // q<5 = W1[k][q], q==5 = b1[k] (bias folded via B1[5][n]=1), rest 0.
    bf16x8 a1f[2];
#pragma unroll
    for (int mt = 0; mt < 2; ++mt) {
        int p = mt * 32 + n32;
        int k = sigma_k(p);
        float w0 = W1[k * 5 + 0], w1 = W1[k * 5 + 1], w2 = W1[k * 5 + 2];
        float w3 = W1[k * 5 + 3], w4 = W1[k * 5 + 4];
        float bc = b1[k];
        uint32_t d0 = pk_bf16(w0, w1);
        uint32_t d1 = pk_bf16(w2, w3);
        uint32_t d2 = pk_bf16(w4, bc);
        if (h) { d0 = 0; d1 = 0; d2 = 0; }
        a1f[mt] = make_frag(d0, d1, d2, 0);
    }

    // Layer2 W2-frags (4 k-tiles), used as the *A* operand of C2^T = W2·h1^T.
    // A[m=n-unit=lane&31][k = 16*kt + 8*h + j] = 8 consecutive floats of
    // W2 row n (32B aligned).
    bf16x8 w2f[4];
#pragma unroll
    for (int kt = 0; kt < 4; ++kt) {
        const float* wp = W2 + n32 * 64 + kt * 16 + h * 8;
        const float4 lo = *(const float4*)(wp);
        const float4 hi = *(const float4*)(wp + 4);
        w2f[kt] = make_frag(pk_bf16(lo.x, lo.y), pk_bf16(lo.z, lo.w),
                            pk_bf16(hi.x, hi.y), pk_bf16(hi.z, hi.w));
    }

    // C2^T C-layout: lane = data-row, reg r -> out-unit n = (r&3)+8*(r>>2)+4*h
    float w3n[16], b2n[16];
#pragma unroll
    for (int r = 0; r < 16; ++r) {
        const int n = (r & 3) + 8 * (r >> 2) + 4 * h;
        w3n[r] = W3[n];
        b2n[r] = b2[n];
    }
    const float b3v = b3[0];

    const int total_waves = NUM_BLOCKS * 4;
    const int w = blockIdx.x * 4 + wid;

    // ---- software-pipelined row loop (prefetch next iter's x) ----
    int it = w;
    const float* xp0 = x + (size_t)(it * ROWS_PER_ITER + n32) * 5;
    float f0 = xp0[0], f1 = xp0[1], f2 = xp0[2], f3 = xp0[3], lp = xp0[4];

    while (true) {
        const int nit = it + total_waves;
        const bool more = nit < NUM_ITERS;
        // prefetch (issued before the dependent compute below)
        const float* nxp = x + (size_t)((more ? nit : it) * ROWS_PER_ITER + n32) * 5;
        const float nf0 = nxp[0], nf1 = nxp[1], nf2 = nxp[2], nf3 = nxp[3],
                    nlp = nxp[4];

        const int rowBase = it * ROWS_PER_ITER;

        // ---- per-lane LayerNorm (both halves redundantly compute row n32) ----
        int lid = (int)(lp * (float)NUM_LAYERS);
        lid = lid < 0 ? 0 : (lid > NUM_LAYERS - 1 ? NUM_LAYERS - 1 : lid);

        const float m  = (f0 + f1 + f2 + f3) * 0.25f;
        const float d0 = f0 - m, d1 = f1 - m, d2 = f2 - m, d3 = f3 - m;
        const float var = (d0 * d0 + d1 * d1 + d2 * d2 + d3 * d3) * 0.25f;
        const float r   = rsqrtf(var + LN_EPS);

        const float4 g  = *(const float4*)(s_ln + lid * 8);
        const float4 bb = *(const float4*)(s_ln + lid * 8 + 4);

        const float xn0 = fmaf(d0 * r, g.x, bb.x);
        const float xn1 = fmaf(d1 * r, g.y, bb.y);
        const float xn2 = fmaf(d2 * r, g.z, bb.z);
        const float xn3 = fmaf(d3 * r, g.w, bb.w);

        // ---- B1 fragment: xn^T, column of 1.0 at q=5 for the b1 fold ----
        uint32_t e0 = pk_bf16(xn0, xn1);
        uint32_t e1 = pk_bf16(xn2, xn3);
        uint32_t e2 = pk_bf16(lp, 1.0f);
        if (h) { e0 = 0; e1 = 0; e2 = 0; }
        const bf16x8 b1f = make_frag(e0, e1, e2, 0);

        // ---- layer 1: h1^T = A1 . xn^T  (2 MFMAs) ----
        f32x16 z;
#pragma unroll
        for (int i = 0; i < 16; ++i) z[i] = 0.0f;
        f32x16 c1a = __builtin_amdgcn_mfma_f32_32x32x16_bf16(a1f[0], b1f, z, 0, 0, 0);
        f32x16 c1b = __builtin_amdgcn_mfma_f32_32x32x16_bf16(a1f[1], b1f, z, 0, 0, 0);

        // ---- relu + repack C1 regs into h1-frags (lane=row, k along regs) ----
        bf16x8 h1f[4];
#pragma unroll
        for (int kt = 0; kt < 4; ++kt) {
            const f32x16& c1 = (kt < 2) ? c1a : c1b;
            const int roff = 8 * (kt & 1);
            uint32_t dw[4];
#pragma unroll
            for (int d = 0; d < 4; ++d) {
                float va = fmaxf(c1[roff + 2 * d], 0.0f);
                float vb = fmaxf(c1[roff + 2 * d + 1], 0.0f);
                dw[d] = pk_bf16(va, vb);
            }
            h1f[kt] = make_frag(dw[0], dw[1], dw[2], dw[3]);
        }

        // ---- layer 2 transposed: C2^T = W2 . h1^T + b2 (4 MFMAs) ----
        f32x16 c2;
#pragma unroll
        for (int i = 0; i < 16; ++i) c2[i] = b2n[i];
#pragma unroll
        for (int kt = 0; kt < 4; ++kt)
            c2 = __builtin_amdgcn_mfma_f32_32x32x16_bf16(w2f[kt], h1f[kt], c2, 0, 0, 0);

        // ---- layer 3: per-lane dot over the 16 regs, then merge halves ----
        float part = 0.0f;
#pragma unroll
        for (int rr = 0; rr < 16; ++rr)
            part = fmaf(fmaxf(c2[rr], 0.0f), w3n[rr], part);
        part += __shfl_xor(part, 32, 64);
        if (!h) out[rowBase + n32] = part + b3v;

        if (!more) break;
        it = nit;
        f0 = nf0; f1 = nf1; f2 = nf2; f3 = nf3; lp = nlp;
    }
}

extern "C" void kernel_launch(void* const* d_in, const int* in_sizes, int n_in,
                              void* d_out, int out_size, void* d_ws, size_t ws_size,
                              hipStream_t stream) {
    const float* x    = (const float*)d_in[0];
    const float* ln_w = (const float*)d_in[1];
    const float* ln_b = (const float*)d_in[2];
    const float* W1   = (const float*)d_in[3];
    const float* b1   = (const float*)d_in[4];
    const float* W2   = (const float*)d_in[5];
    const float* b2   = (const float*)d_in[6];
    const float* W3   = (const float*)d_in[7];
    const float* b3   = (const float*)d_in[8];
    float* out = (float*)d_out;

    router_mfma<<<NUM_BLOCKS, 256, 0, stream>>>(x, ln_w, ln_b, W1, b1, W2, b2,
                                                W3, b3, out);
}

// Round 4
// 117.680 us; speedup vs baseline: 2.0300x; 1.0415x over previous
//
#include <hip/hip_runtime.h>
#include <hip/hip_bf16.h>
#include <stdint.h>

#define NUM_LAYERS 24
#define LN_EPS 1e-5f
#define N_ROWS (256 * 8192)
#define ROWS_PER_ITER 64
#define NUM_ITERS (N_ROWS / ROWS_PER_ITER)   // 32768
#define NUM_BLOCKS 2048                       // 8192 waves -> 4 iters/wave

typedef __attribute__((ext_vector_type(8)))  short bf16x8;   // 8 bf16 = 4 VGPRs
typedef __attribute__((ext_vector_type(16))) float f32x16;   // 32x32 MFMA acc
typedef __attribute__((ext_vector_type(2)))  float f32x2;

// pack two f32 -> one dword of 2 bf16 (lo = first arg), RNE
__device__ __forceinline__ uint32_t pk_bf16(float lo, float hi) {
    __hip_bfloat162 h2 = __float22bfloat162_rn(float2{lo, hi});
    uint32_t u;
    __builtin_memcpy(&u, &h2, 4);
    return u;
}

union FragU { bf16x8 f; uint32_t u[4]; };

__device__ __forceinline__ bf16x8 make_frag(uint32_t d0, uint32_t d1,
                                            uint32_t d2, uint32_t d3) {
    FragU fu;
    fu.u[0] = d0; fu.u[1] = d1; fu.u[2] = d2; fu.u[3] = d3;
    return fu.f;
}

// canonical hidden index k placed at layer1-output row-position p (sigma).
// C1 (32x32 C-layout) reg r, lane-half hh, m-tile mt holds position
// p = 32*mt + (r&3) + 8*(r>>2) + 4*hh. We need that position to carry
// canonical k = 16*(2*mt + (r>>3)) + 8*hh + (r&7) so that the layer2
// h1-fragment slot (kt = 2*mt + (r>>3), j = r&7) is correct for BOTH halves.
__device__ __forceinline__ int sigma_k(int p) {
    int hh = (p >> 2) & 1;
    int base = (p & 31) - 4 * hh;            // in {0-3,8-11,16-19,24-27}
    int r = (base & 3) + 4 * (base >> 3);    // in [0,16)
    return 32 * (p >> 5) + 16 * (r >> 3) + 8 * hh + (r & 7);
}

__global__ __launch_bounds__(256, 3) void router_mfma(
    const float* __restrict__ x,
    const float* __restrict__ ln_w,
    const float* __restrict__ ln_b,
    const float* __restrict__ W1,
    const float* __restrict__ b1,
    const float* __restrict__ W2,
    const float* __restrict__ b2,
    const float* __restrict__ W3,
    const float* __restrict__ b3,
    float* __restrict__ out)
{
    // ln_w/ln_b interleaved per lid: [g0..g3, b0..b3] (32B per lid)
    __shared__ float s_ln[NUM_LAYERS * 8];
    const int t = threadIdx.x;
    if (t < NUM_LAYERS * 4) {
        int lid = t >> 2, c = t & 3;
        s_ln[lid * 8 + c]     = ln_w[t];
        s_ln[lid * 8 + 4 + c] = ln_b[t];
    }
    __syncthreads();

    const int lane = t & 63;
    const int wid  = t >> 6;
    const int n32  = lane & 31;
    const int h    = lane >> 5;

    // ---------- preload weight fragments (once per thread) ----------
    bf16x8 a1f[2];
#pragma unroll
    for (int mt = 0; mt < 2; ++mt) {
        int p = mt * 32 + n32;
        int k = sigma_k(p);
        float w0 = W1[k * 5 + 0], w1 = W1[k * 5 + 1], w2 = W1[k * 5 + 2];
        float w3 = W1[k * 5 + 3], w4 = W1[k * 5 + 4];
        float bc = b1[k];
        uint32_t d0 = pk_bf16(w0, w1);
        uint32_t d1 = pk_bf16(w2, w3);
        uint32_t d2 = pk_bf16(w4, bc);
        if (h) { d0 = 0; d1 = 0; d2 = 0; }
        a1f[mt] = make_frag(d0, d1, d2, 0);
    }

    // Layer2 W2-frags (4 k-tiles), A operand of C2^T = W2·h1^T.
    bf16x8 w2f[4];
#pragma unroll
    for (int kt = 0; kt < 4; ++kt) {
        const float* wp = W2 + n32 * 64 + kt * 16 + h * 8;
        const float4 lo = *(const float4*)(wp);
        const float4 hi = *(const float4*)(wp + 4);
        w2f[kt] = make_frag(pk_bf16(lo.x, lo.y), pk_bf16(lo.z, lo.w),
                            pk_bf16(hi.x, hi.y), pk_bf16(hi.z, hi.w));
    }

    // C2^T C-layout: lane = data-row, reg r -> out-unit n = (r&3)+8*(r>>2)+4*h
    // pair r2 covers regs {2r2, 2r2+1} -> consecutive units n0, n0+1.
    f32x2 w3p[8], b2p[8];
#pragma unroll
    for (int r2 = 0; r2 < 8; ++r2) {
        const int r = 2 * r2;
        const int n = (r & 3) + 8 * (r >> 2) + 4 * h;
        w3p[r2] = f32x2{W3[n], W3[n + 1]};
        b2p[r2] = f32x2{b2[n], b2[n + 1]};
    }
    const float b3v = b3[0];

    f32x16 zf;
#pragma unroll
    for (int i = 0; i < 16; ++i) zf[i] = 0.0f;
    const f32x2 z2 = {0.0f, 0.0f};

    const int total_waves = NUM_BLOCKS * 4;
    const int w = blockIdx.x * 4 + wid;

    // ---- software-pipelined row loop; each lane LNs ONE distinct row ----
    int it = w;
    const float* xp0 = x + (size_t)(it * ROWS_PER_ITER + lane) * 5;
    float f0 = xp0[0], f1 = xp0[1], f2 = xp0[2], f3 = xp0[3], lp = xp0[4];

    while (true) {
        const int nit = it + total_waves;
        const bool more = nit < NUM_ITERS;
        const float* nxp =
            x + (size_t)((more ? nit : it) * ROWS_PER_ITER + lane) * 5;
        const float nf0 = nxp[0], nf1 = nxp[1], nf2 = nxp[2], nf3 = nxp[3],
                    nlp = nxp[4];

        const int rowBase = it * ROWS_PER_ITER;

        // ---- LayerNorm of row (rowBase + lane) ----
        int lid = (int)(lp * (float)NUM_LAYERS);
        lid = lid < 0 ? 0 : (lid > NUM_LAYERS - 1 ? NUM_LAYERS - 1 : lid);

        const float m  = (f0 + f1 + f2 + f3) * 0.25f;
        const float d0 = f0 - m, d1 = f1 - m, d2 = f2 - m, d3 = f3 - m;
        const float var = (d0 * d0 + d1 * d1 + d2 * d2 + d3 * d3) * 0.25f;
        const float r   = rsqrtf(var + LN_EPS);

        const float4 g  = *(const float4*)(s_ln + lid * 8);
        const float4 bb = *(const float4*)(s_ln + lid * 8 + 4);

        const float xn0 = fmaf(d0 * r, g.x, bb.x);
        const float xn1 = fmaf(d1 * r, g.y, bb.y);
        const float xn2 = fmaf(d2 * r, g.z, bb.z);
        const float xn3 = fmaf(d3 * r, g.w, bb.w);

        // packed normed features (+ 1.0 slot for the b1 fold)
        const uint32_t e0 = pk_bf16(xn0, xn1);
        const uint32_t e1 = pk_bf16(xn2, xn3);
        const uint32_t e2 = pk_bf16(lp, 1.0f);
        // other half's rows
        const uint32_t x0 = __shfl_xor((int)e0, 32, 64);
        const uint32_t x1 = __shfl_xor((int)e1, 32, 64);
        const uint32_t x2 = __shfl_xor((int)e2, 32, 64);

        // tile0 = rows 0..31 (values live on h=0 lanes), tile1 = rows 32..63
        const bf16x8 bf_t0 = make_frag(h ? 0u : e0, h ? 0u : e1, h ? 0u : e2, 0u);
        const bf16x8 bf_t1 = make_frag(h ? 0u : x0, h ? 0u : x1, h ? 0u : x2, 0u);

        float res[2];
#pragma unroll
        for (int tile = 0; tile < 2; ++tile) {
            const bf16x8 b1f = tile ? bf_t1 : bf_t0;

            // layer 1: h1^T = A1 . xn^T (2 MFMAs)
            f32x16 c1a = __builtin_amdgcn_mfma_f32_32x32x16_bf16(a1f[0], b1f, zf, 0, 0, 0);
            f32x16 c1b = __builtin_amdgcn_mfma_f32_32x32x16_bf16(a1f[1], b1f, zf, 0, 0, 0);

            // relu + repack C1 regs into h1-frags (lane=row, k along regs)
            bf16x8 h1f[4];
#pragma unroll
            for (int kt = 0; kt < 4; ++kt) {
                const f32x16& c1 = (kt < 2) ? c1a : c1b;
                const int roff = 8 * (kt & 1);
                uint32_t dw[4];
#pragma unroll
                for (int d = 0; d < 4; ++d) {
                    f32x2 v = {c1[roff + 2 * d], c1[roff + 2 * d + 1]};
                    v = __builtin_elementwise_max(v, z2);
                    dw[d] = pk_bf16(v.x, v.y);
                }
                h1f[kt] = make_frag(dw[0], dw[1], dw[2], dw[3]);
            }

            // layer 2 transposed: C2^T = W2 . h1^T (4 MFMAs, C starts at 0)
            f32x16 c2 = __builtin_amdgcn_mfma_f32_32x32x16_bf16(w2f[0], h1f[0], zf, 0, 0, 0);
#pragma unroll
            for (int kt = 1; kt < 4; ++kt)
                c2 = __builtin_amdgcn_mfma_f32_32x32x16_bf16(w2f[kt], h1f[kt], c2, 0, 0, 0);

            // layer 3: packed (c2 + b2) -> relu -> dot W3 over 16 regs
            f32x2 acc = z2;
#pragma unroll
            for (int r2 = 0; r2 < 8; ++r2) {
                f32x2 v = {c2[2 * r2], c2[2 * r2 + 1]};
                v = v + b2p[r2];
                v = __builtin_elementwise_max(v, z2);
                acc = v * w3p[r2] + acc;
            }
            float part = acc.x + acc.y;
            part += __shfl_xor(part, 32, 64);
            res[tile] = part + b3v;
        }

        // lane stores its own row: h=0 lanes tile0 row n32, h=1 tile1 row n32
        out[rowBase + lane] = (h ? res[1] : res[0]) + 0.0f;

        if (!more) break;
        it = nit;
        f0 = nf0; f1 = nf1; f2 = nf2; f3 = nf3; lp = nlp;
    }
}

extern "C" void kernel_launch(void* const* d_in, const int* in_sizes, int n_in,
                              void* d_out, int out_size, void* d_ws, size_t ws_size,
                              hipStream_t stream) {
    const float* x    = (const float*)d_in[0];
    const float* ln_w = (const float*)d_in[1];
    const float* ln_b = (const float*)d_in[2];
    const float* W1   = (const float*)d_in[3];
    const float* b1   = (const float*)d_in[4];
    const float* W2   = (const float*)d_in[5];
    const float* b2   = (const float*)d_in[6];
    const float* W3   = (const float*)d_in[7];
    const float* b3   = (const float*)d_in[8];
    float* out = (float*)d_out;

    router_mfma<<<NUM_BLOCKS, 256, 0, stream>>>(x, ln_w, ln_b, W1, b1, W2, b2,
                                                W3, b3, out);
}